// Round 2
// baseline (3996.904 us; speedup 1.0000x reference)
//
#include <hip/hip_runtime.h>

namespace {

constexpr int Bn = 32, Cn = 8, Hn = 512, In = 512;
constexpr size_t HI = (size_t)Hn * In;

__device__ __forceinline__ float actf(float x) {
    // hardtanh: (|x+1| - |x-1|)/2 == clamp(x, -1, 1)
    return fminf(1.0f, fmaxf(-1.0f, x));
}

// ---------------------------------------------------------------------------
// Batched GEMM: C[bc] = act( A @ (B[bc] * scale * act(mask)) )
// A: [Hn,Hn] shared across batches, B/C: [nb, Hn, In]
// 64x64 tile, BK=16, 256 threads, 4x4 per thread.
// ---------------------------------------------------------------------------
template<bool MASK>
__global__ __launch_bounds__(256) void gemm_bat(
    const float* __restrict__ A,
    const float* __restrict__ Bmat,
    const float* __restrict__ mask,
    float* __restrict__ Cmat,
    float scale)
{
    const int bc = blockIdx.z;
    const float* Bp = Bmat + (size_t)bc * HI;
    float* Cp = Cmat + (size_t)bc * HI;
    const int n0 = blockIdx.x * 64;
    const int m0 = blockIdx.y * 64;

    __shared__ __align__(16) float As[16][68];
    __shared__ __align__(16) float Bs[16][68];

    const int tid = threadIdx.x;
    const int tx = tid & 15, ty = tid >> 4;

    float acc[4][4] = {};

    for (int k0 = 0; k0 < Hn; k0 += 16) {
        #pragma unroll
        for (int l = tid; l < 64 * 16; l += 256) {   // A tile: 64 m x 16 k
            int m = l >> 4, k = l & 15;
            As[k][m] = A[(m0 + m) * Hn + k0 + k];
        }
        #pragma unroll
        for (int l = tid; l < 16 * 64; l += 256) {   // B tile: 16 k x 64 n
            int k = l >> 6, n = l & 63;
            float v = Bp[(size_t)(k0 + k) * In + n0 + n] * scale;
            if (MASK) v *= actf(mask[(k0 + k) * In + n0 + n]);
            Bs[k][n] = v;
        }
        __syncthreads();
        #pragma unroll
        for (int k = 0; k < 16; ++k) {
            float4 av = *(const float4*)&As[k][ty * 4];
            float4 bv = *(const float4*)&Bs[k][tx * 4];
            float a_[4] = {av.x, av.y, av.z, av.w};
            float b_[4] = {bv.x, bv.y, bv.z, bv.w};
            #pragma unroll
            for (int i = 0; i < 4; ++i)
                #pragma unroll
                for (int j = 0; j < 4; ++j)
                    acc[i][j] = fmaf(a_[i], b_[j], acc[i][j]);
        }
        __syncthreads();
    }

    #pragma unroll
    for (int i = 0; i < 4; ++i) {
        float4 v = make_float4(actf(acc[i][0]), actf(acc[i][1]),
                               actf(acc[i][2]), actf(acc[i][3]));
        *(float4*)&Cp[(size_t)(m0 + ty * 4 + i) * In + n0 + tx * 4] = v;
    }
}

// ---------------------------------------------------------------------------
// Row GEMM vs transposed weight: Out[r,n] = epi( sum_k u(r,k)*W[n,k] + bias[n] )
// u(r,k) = PRE ? act(rowscale[(r % Hn)] * U[r,k]) : U[r,k]
// U: [R, In] (R = gridDim.y*64), W: [In, In] row-major (N,K), Out: [R, In]
// EPI: 0=none, 1=act, 2=relu
// ---------------------------------------------------------------------------
template<int EPI, bool PRE>
__global__ __launch_bounds__(256) void gemm_rw(
    const float* __restrict__ U,
    const float* __restrict__ W,
    const float* __restrict__ bias,
    const float* __restrict__ rowscale,
    float* __restrict__ Out)
{
    const int n0 = blockIdx.x * 64;
    const int r0 = blockIdx.y * 64;
    const int hbase = r0 & (Hn - 1);     // r0 % Hn (both multiples of 64)

    __shared__ __align__(16) float Us[16][68];
    __shared__ __align__(16) float Ws[16][68];

    const int tid = threadIdx.x;
    const int tx = tid & 15, ty = tid >> 4;

    float acc[4][4] = {};

    for (int k0 = 0; k0 < In; k0 += 16) {
        #pragma unroll
        for (int l = tid; l < 64 * 16; l += 256) {   // U tile (transpose to [k][r])
            int r = l >> 4, k = l & 15;
            float v = U[(size_t)(r0 + r) * In + k0 + k];
            if (PRE) v = actf(rowscale[hbase + r] * v);
            Us[k][r] = v;
        }
        #pragma unroll
        for (int l = tid; l < 64 * 16; l += 256) {   // W tile (transpose to [k][n])
            int n = l >> 4, k = l & 15;
            Ws[k][n] = W[(size_t)(n0 + n) * In + k0 + k];
        }
        __syncthreads();
        #pragma unroll
        for (int k = 0; k < 16; ++k) {
            float4 av = *(const float4*)&Us[k][ty * 4];
            float4 bv = *(const float4*)&Ws[k][tx * 4];
            float a_[4] = {av.x, av.y, av.z, av.w};
            float b_[4] = {bv.x, bv.y, bv.z, bv.w};
            #pragma unroll
            for (int i = 0; i < 4; ++i)
                #pragma unroll
                for (int j = 0; j < 4; ++j)
                    acc[i][j] = fmaf(a_[i], b_[j], acc[i][j]);
        }
        __syncthreads();
    }

    #pragma unroll
    for (int i = 0; i < 4; ++i) {
        float r_[4];
        #pragma unroll
        for (int j = 0; j < 4; ++j) {
            float v = acc[i][j] + bias[n0 + tx * 4 + j];
            if (EPI == 1) v = actf(v);
            if (EPI == 2) v = fmaxf(v, 0.0f);
            r_[j] = v;
        }
        *(float4*)&Out[(size_t)(r0 + ty * 4 + i) * In + n0 + tx * 4] =
            make_float4(r_[0], r_[1], r_[2], r_[3]);
    }
}

// ---------------------------------------------------------------------------
// Channel reduction. FIRST: comb[b] = x0[b]*(1/5000) + sum_c T[b,c]
//                   else : comb[b] += sum_c T[b,c]
// ---------------------------------------------------------------------------
template<bool FIRST>
__global__ __launch_bounds__(256) void reduce_c(
    const float* __restrict__ T,     // [nb*Cn, HI]
    const float* __restrict__ x0,    // [nb, Cn, HI], channel 0 used (null if !FIRST)
    float* __restrict__ comb)        // [nb, HI]
{
    size_t idx = (size_t)blockIdx.x * 256 + threadIdx.x;   // float4 index
    size_t b = idx / (HI / 4);
    size_t p = (idx % (HI / 4)) * 4;

    float4 s;
    if (FIRST) {
        float4 xv = *(const float4*)&x0[b * Cn * HI + p];
        const float sc = 1.0f / 5000.0f;
        s = make_float4(xv.x * sc, xv.y * sc, xv.z * sc, xv.w * sc);
    } else {
        s = *(const float4*)&comb[b * HI + p];
    }
    #pragma unroll
    for (int c = 0; c < Cn; ++c) {
        float4 t = *(const float4*)&T[(b * Cn + c) * HI + p];
        s.x += t.x; s.y += t.y; s.z += t.z; s.w += t.w;
    }
    *(float4*)&comb[b * HI + p] = s;
}

__global__ __launch_bounds__(256) void prep_wpe(
    const float* __restrict__ Wp, const float* __restrict__ Wpd,
    float* __restrict__ Wpe)
{
    int idx = blockIdx.x * 256 + threadIdx.x;
    int i = idx / Hn, j = idx % Hn;
    Wpe[idx] = Wp[idx] + (i == j ? Wpd[i] : 0.0f);
}

// zrow[h] = sum_k Wzp[h,k]   (einsum 'hk,bchi->bchi' == rowsum scale)
__global__ __launch_bounds__(64) void rowsum(
    const float* __restrict__ Wzp, float* __restrict__ zrow)
{
    const int h = blockIdx.x;
    const int lane = threadIdx.x;
    float s = 0.0f;
    for (int k = lane; k < Hn; k += 64) s += Wzp[h * Hn + k];
    #pragma unroll
    for (int off = 32; off > 0; off >>= 1) s += __shfl_down(s, off, 64);
    if (lane == 0) zrow[h] = s;
}

} // namespace

extern "C" void kernel_launch(void* const* d_in, const int* in_sizes, int n_in,
                              void* d_out, int out_size, void* d_ws, size_t ws_size,
                              hipStream_t stream)
{
    const float* input  = (const float*)d_in[0];   // [B,C,H,I]
    const float* p_mask = (const float*)d_in[1];   // [H,I]
    const float* Wp     = (const float*)d_in[2];   // [H,H]
    const float* Wpd    = (const float*)d_in[3];   // [H]
    const float* Wzp    = (const float*)d_in[4];   // [H,H]
    const float* plw    = (const float*)d_in[5];
    const float* plb    = (const float*)d_in[6];
    const float* zlw    = (const float*)d_in[7];
    const float* zlb    = (const float*)d_in[8];
    const float* f1w    = (const float*)d_in[9];
    const float* f1b    = (const float*)d_in[10];
    const float* f2w    = (const float*)d_in[11];
    const float* f2b    = (const float*)d_in[12];
    float* out = (float*)d_out;

    // Workspace layout: [Wpe | zrow | comb | out1 | W0 | W1]
    float* ws   = (float*)d_ws;
    float* Wpe  = ws;
    float* zrow = Wpe + (size_t)Hn * Hn;
    float* comb = zrow + Hn;
    float* out1 = comb + (size_t)Bn * HI;
    float* W0   = out1 + (size_t)Bn * HI;

    size_t fixed = (size_t)Hn * Hn + Hn + 2 * (size_t)Bn * HI;
    size_t ws_f  = ws_size / sizeof(float);
    size_t avail = ws_f > fixed ? ws_f - fixed : 0;
    int chunk = 32;                                   // batch-chunk (divides 32)
    while (chunk > 1 && 2 * (size_t)chunk * Cn * HI > avail) chunk >>= 1;
    float* W1 = W0 + (size_t)chunk * Cn * HI;

    prep_wpe<<<Hn * Hn / 256, 256, 0, stream>>>(Wp, Wpd, Wpe);
    rowsum<<<Hn, 64, 0, stream>>>(Wzp, zrow);

    for (int b0 = 0; b0 < Bn; b0 += chunk) {
        const int nb  = chunk;
        const int nbc = nb * Cn;
        const float* inp_c = input + (size_t)b0 * Cn * HI;
        dim3 gb(In / 64, Hn / 64, nbc);
        dim3 gr(In / 64, (unsigned)((size_t)nbc * Hn / 64));
        unsigned gred = (unsigned)((size_t)nb * HI / 4 / 256);

        // W0 = act(Wp_eff @ (x * act(p_mask) / 5000))
        gemm_bat<true><<<gb, 256, 0, stream>>>(Wpe, inp_c, p_mask, W0, 1.0f / 5000.0f);
        // W1 = tp = act(W0 @ p_lin_w^T + p_lin_b)
        gemm_rw<1, false><<<gr, 256, 0, stream>>>(W0, plw, plb, nullptr, W1);
        // comb = x[:,0]/5000 + sum_c tp
        reduce_c<true><<<gred, 256, 0, stream>>>(W1, inp_c, comb + (size_t)b0 * HI);
        // W0 = tz = act( act(zrow[h] * tp) @ z_lin_w^T + z_lin_b )
        gemm_rw<1, true><<<gr, 256, 0, stream>>>(W1, zlw, zlb, zrow, W0);
        // comb += sum_c tz
        reduce_c<false><<<gred, 256, 0, stream>>>(W0, nullptr, comb + (size_t)b0 * HI);
    }

    dim3 gf(In / 64, (unsigned)((size_t)Bn * Hn / 64));
    // out1 = relu(comb @ fc1_w^T + fc1_b)
    gemm_rw<2, false><<<gf, 256, 0, stream>>>(comb, f1w, f1b, nullptr, out1);
    // out = out1 @ fc2_w^T + fc2_b
    gemm_rw<0, false><<<gf, 256, 0, stream>>>(out1, f2w, f2b, nullptr, out);
}

// Round 3
// 618.134 us; speedup vs baseline: 6.4661x; 6.4661x over previous
//
#include <hip/hip_runtime.h>

namespace {

constexpr int Bn = 32, Cn = 8, Hn = 512, In = 512;
constexpr size_t HI = (size_t)Hn * In;     // 262144
constexpr float SC = 1.0f / 5000.0f;

using s16x8 = __attribute__((ext_vector_type(8))) short;
using f32x4 = __attribute__((ext_vector_type(4))) float;

__device__ __forceinline__ float actf(float x) {
    return fminf(1.0f, fmaxf(-1.0f, x));   // hardtanh
}

__device__ __forceinline__ unsigned short f2bf(float f) {   // RNE f32->bf16
    unsigned u = __builtin_bit_cast(unsigned, f);
    u += 0x7FFFu + ((u >> 16) & 1u);
    return (unsigned short)(u >> 16);
}
__device__ __forceinline__ float bf2f(unsigned short h) {
    return __builtin_bit_cast(float, (unsigned)h << 16);
}

__device__ __forceinline__ void async16(const void* g, void* l) {
    __builtin_amdgcn_global_load_lds(
        (const __attribute__((address_space(1))) unsigned*)g,
        (__attribute__((address_space(3))) unsigned*)l, 16, 0, 0);
}

// ---------------------------------------------------------------------------
// bf16 MFMA GEMM, m97 structure: 128x128 tile, BK=32, 4 waves, N=K=512 fixed.
// C = A[M,512] @ Bt[512cols,512k]^T, fp32 accum.
// EPI: 0: out0=bf16(act(acc))                              (G1, no bias)
//      1: v=act(acc+bias); out0=bf16(v); out1=bf16(act(zrow[r&511]*v)) (G2)
//      2: out0=bf16(act(acc+bias))                          (G3)
//      3: out0=bf16(relu(acc+bias))                         (G4)
//      4: outf=acc+bias (fp32)                              (G5)
// ---------------------------------------------------------------------------
template<int EPI>
__global__ __launch_bounds__(256) void mfma_gemm(
    const unsigned short* __restrict__ A,
    const unsigned short* __restrict__ Bt,
    const float* __restrict__ bias,
    const float* __restrict__ zrow,
    unsigned short* __restrict__ out0,
    unsigned short* __restrict__ out1,
    float* __restrict__ outf,
    size_t sA, size_t sB, size_t sC)
{
    __shared__ __align__(16) unsigned short As[128 * 32];
    __shared__ __align__(16) unsigned short Bs[128 * 32];

    const int tid  = threadIdx.x;
    const int wid  = tid >> 6, lane = tid & 63;
    const int wr   = wid >> 1, wc = wid & 1;
    const size_t zb = blockIdx.z;

    const char* Ab = (const char*)(A + zb * sA) + (size_t)blockIdx.y * 128 * 1024;
    const char* Bb = (const char*)(Bt + zb * sB) + (size_t)blockIdx.x * 128 * 1024;

    f32x4 acc[4][4] = {};

    const int o0  = tid * 16;         // staging instr 0: linear byte in tile
    const int r0s = o0 >> 6;          // tile row (64B per row = 32 bf16)
    const int c0s = o0 & 63;          // byte within row

    for (int k0 = 0; k0 < 512; k0 += 32) {
        // ---- stage A/B tiles (128 rows x 32 k, bf16, linear) ----
        async16(Ab + (size_t)r0s * 1024 + k0 * 2 + c0s,        (char*)As + wid * 1024);
        async16(Ab + (size_t)(64 + r0s) * 1024 + k0 * 2 + c0s, (char*)As + 4096 + wid * 1024);
        async16(Bb + (size_t)r0s * 1024 + k0 * 2 + c0s,        (char*)Bs + wid * 1024);
        async16(Bb + (size_t)(64 + r0s) * 1024 + k0 * 2 + c0s, (char*)Bs + 4096 + wid * 1024);
        __syncthreads();

        // ---- fragments + MFMA ----
        s16x8 a[4], b[4];
        const int kc = (lane >> 4) * 16;            // k-chunk byte offset
        const int ar = wr * 64 + (lane & 15);
        const int br = wc * 64 + (lane & 15);
        #pragma unroll
        for (int m = 0; m < 4; ++m)
            a[m] = *(const s16x8*)((const char*)As + (size_t)(ar + m * 16) * 64 + kc);
        #pragma unroll
        for (int n = 0; n < 4; ++n)
            b[n] = *(const s16x8*)((const char*)Bs + (size_t)(br + n * 16) * 64 + kc);
        #pragma unroll
        for (int m = 0; m < 4; ++m)
            #pragma unroll
            for (int n = 0; n < 4; ++n)
                acc[m][n] = __builtin_amdgcn_mfma_f32_16x16x32_bf16(a[m], b[n], acc[m][n], 0, 0, 0);
        __syncthreads();
    }

    // ---- epilogue: C/D layout col=lane&15, row=(lane>>4)*4+j ----
    const int cb = blockIdx.x * 128 + wc * 64 + (lane & 15);
    const int rb = blockIdx.y * 128 + wr * 64 + ((lane >> 4) << 2);
    #pragma unroll
    for (int m = 0; m < 4; ++m) {
        #pragma unroll
        for (int n = 0; n < 4; ++n) {
            const int c = cb + n * 16;
            #pragma unroll
            for (int j = 0; j < 4; ++j) {
                const int r = rb + m * 16 + j;
                float v = acc[m][n][j];
                const size_t idx = zb * sC + (size_t)r * 512 + c;
                if (EPI == 0) {
                    out0[idx] = f2bf(actf(v));
                } else if (EPI == 1) {
                    v = actf(v + bias[c]);
                    out0[idx] = f2bf(v);
                    out1[idx] = f2bf(actf(zrow[r & 511] * v));
                } else if (EPI == 2) {
                    out0[idx] = f2bf(actf(v + bias[c]));
                } else if (EPI == 3) {
                    out0[idx] = f2bf(fmaxf(v + bias[c], 0.0f));
                } else {
                    outf[idx] = v + bias[c];
                }
            }
        }
    }
}

// ---------------------------------------------------------------------------
// xst[bc][i][k] = bf16( x[bc][k][i] * act(mask[k][i]) / 5000 )   (64x64 tiles)
// ---------------------------------------------------------------------------
__global__ __launch_bounds__(256) void transpose_mask(
    const float* __restrict__ x, const float* __restrict__ mask,
    unsigned short* __restrict__ xst)
{
    __shared__ float t[64][65];
    const int bc = blockIdx.z;
    const int i0 = blockIdx.x * 64, k0 = blockIdx.y * 64;
    const int r4 = threadIdx.x >> 6, cc = threadIdx.x & 63;
    const float* xp = x + (size_t)bc * HI;
    #pragma unroll
    for (int it = 0; it < 16; ++it) {
        int kl = it * 4 + r4;
        size_t g = (size_t)(k0 + kl) * In + i0 + cc;
        t[kl][cc] = xp[g] * (actf(mask[g]) * SC);
    }
    __syncthreads();
    unsigned short* op = xst + (size_t)bc * HI;
    #pragma unroll
    for (int it = 0; it < 16; ++it) {
        int il = it * 4 + r4;
        op[(size_t)(i0 + il) * Hn + k0 + cc] = f2bf(t[cc][il]);
    }
}

// comb[b] = bf16( x0[b]/5000 + sum_c tp[b,c] + sum_c tz[b,c] )
__global__ __launch_bounds__(256) void reduce_both(
    const unsigned short* __restrict__ tp,
    const unsigned short* __restrict__ tz,
    const float* __restrict__ x0,
    unsigned short* __restrict__ comb)
{
    size_t idx = (size_t)blockIdx.x * 256 + threadIdx.x;   // float4 slot
    size_t b = idx >> 16;                                  // / (HI/4)
    size_t p = (idx & 65535) * 4;
    float4 xv = *(const float4*)&x0[(b * Cn) * HI + p];
    float s0 = xv.x * SC, s1 = xv.y * SC, s2 = xv.z * SC, s3 = xv.w * SC;
    #pragma unroll
    for (int c = 0; c < Cn; ++c) {
        size_t q = (b * Cn + c) * HI + p;
        ushort4 a = *(const ushort4*)&tp[q];
        ushort4 d = *(const ushort4*)&tz[q];
        s0 += bf2f(a.x) + bf2f(d.x);
        s1 += bf2f(a.y) + bf2f(d.y);
        s2 += bf2f(a.z) + bf2f(d.z);
        s3 += bf2f(a.w) + bf2f(d.w);
    }
    ushort4 o;
    o.x = f2bf(s0); o.y = f2bf(s1); o.z = f2bf(s2); o.w = f2bf(s3);
    *(ushort4*)&comb[b * HI + p] = o;
}

__global__ __launch_bounds__(256) void prep_wpe_bf(
    const float* __restrict__ Wp, const float* __restrict__ Wpd,
    unsigned short* __restrict__ o)
{
    int idx = blockIdx.x * 256 + threadIdx.x;
    int i = idx >> 9, j = idx & 511;
    o[idx] = f2bf(Wp[idx] + (i == j ? Wpd[i] : 0.0f));
}

__global__ __launch_bounds__(256) void conv_bf(
    const float* __restrict__ s, unsigned short* __restrict__ o)
{
    int idx = blockIdx.x * 256 + threadIdx.x;
    o[idx] = f2bf(s[idx]);
}

__global__ __launch_bounds__(64) void rowsum(
    const float* __restrict__ W, float* __restrict__ zr)
{
    int h = blockIdx.x, l = threadIdx.x;
    float s = 0.0f;
    for (int k = l; k < Hn; k += 64) s += W[h * Hn + k];
    #pragma unroll
    for (int off = 32; off; off >>= 1) s += __shfl_down(s, off, 64);
    if (!l) zr[h] = s;
}

} // namespace

extern "C" void kernel_launch(void* const* d_in, const int* in_sizes, int n_in,
                              void* d_out, int out_size, void* d_ws, size_t ws_size,
                              hipStream_t stream)
{
    const float* input  = (const float*)d_in[0];
    const float* p_mask = (const float*)d_in[1];
    const float* Wp     = (const float*)d_in[2];
    const float* Wpd    = (const float*)d_in[3];
    const float* Wzp    = (const float*)d_in[4];
    const float* plw    = (const float*)d_in[5];
    const float* plb    = (const float*)d_in[6];
    const float* zlw    = (const float*)d_in[7];
    const float* zlb    = (const float*)d_in[8];
    const float* f1w    = (const float*)d_in[9];
    const float* f1b    = (const float*)d_in[10];
    const float* f2w    = (const float*)d_in[11];
    const float* f2b    = (const float*)d_in[12];

    constexpr size_t WB  = 512 * 512 * 2;        // one bf16 weight matrix
    constexpr size_t CMB = (size_t)Bn * HI * 2;  // comb / out1 (bf16)

    char* w = (char*)d_ws;
    auto alloc = [&](size_t bytes) { char* p = w; w += (bytes + 255) & ~255ull; return p; };

    unsigned short* Wpe  = (unsigned short*)alloc(WB);
    unsigned short* plwb = (unsigned short*)alloc(WB);
    unsigned short* zlwb = (unsigned short*)alloc(WB);
    unsigned short* f1wb = (unsigned short*)alloc(WB);
    unsigned short* f2wb = (unsigned short*)alloc(WB);
    float*          zrw  = (float*)alloc(512 * 4);
    unsigned short* comb = (unsigned short*)alloc(CMB);
    unsigned short* o1b  = (unsigned short*)alloc(CMB);

    size_t fixedB = (size_t)(w - (char*)d_ws);
    int chunk = 32;
    while (chunk > 1 &&
           fixedB + 4ull * (size_t)chunk * Cn * HI * 2 + 4096 > ws_size)
        chunk >>= 1;
    const size_t CB = (size_t)chunk * Cn * HI * 2;   // per chunk buffer bytes
    unsigned short* xst   = (unsigned short*)alloc(CB);   // also reused for tz
    unsigned short* tpact = (unsigned short*)alloc(CB);
    unsigned short* tpb   = (unsigned short*)alloc(CB);
    unsigned short* tzin  = (unsigned short*)alloc(CB);
    unsigned short* tzb   = xst;

    prep_wpe_bf<<<512 * 512 / 256, 256, 0, stream>>>(Wp, Wpd, Wpe);
    conv_bf<<<1024, 256, 0, stream>>>(plw, plwb);
    conv_bf<<<1024, 256, 0, stream>>>(zlw, zlwb);
    conv_bf<<<1024, 256, 0, stream>>>(f1w, f1wb);
    conv_bf<<<1024, 256, 0, stream>>>(f2w, f2wb);
    rowsum<<<512, 64, 0, stream>>>(Wzp, zrw);

    for (int b0 = 0; b0 < Bn; b0 += chunk) {
        const int nc = chunk * Cn;
        const float* inp_c = input + (size_t)b0 * Cn * HI;

        // xst = bf16(x^T * act(mask)/5000)
        transpose_mask<<<dim3(8, 8, nc), 256, 0, stream>>>(inp_c, p_mask, xst);
        // tpact = act(Wpe @ p_set)
        mfma_gemm<0><<<dim3(4, 4, nc), 256, 0, stream>>>(
            Wpe, xst, nullptr, nullptr, tpact, nullptr, nullptr, 0, HI, HI);
        // tp = act(tpact @ plw^T + plb); tzin = act(zrow*tp)
        mfma_gemm<1><<<dim3(4, nc * 4, 1), 256, 0, stream>>>(
            tpact, plwb, plb, zrw, tpb, tzin, nullptr, 0, 0, 0);
        // tz = act(tzin @ zlw^T + zlb)
        mfma_gemm<2><<<dim3(4, nc * 4, 1), 256, 0, stream>>>(
            tzin, zlwb, zlb, nullptr, tzb, nullptr, nullptr, 0, 0, 0);
        // comb = x0/5000 + sum_c tp + sum_c tz
        reduce_both<<<chunk * 256, 256, 0, stream>>>(
            tpb, tzb, inp_c, comb + (size_t)b0 * HI);
    }

    // out1 = relu(comb @ f1w^T + f1b)
    mfma_gemm<3><<<dim3(4, 128, 1), 256, 0, stream>>>(
        comb, f1wb, f1b, nullptr, o1b, nullptr, nullptr, 0, 0, 0);
    // out = out1 @ f2w^T + f2b   (fp32)
    mfma_gemm<4><<<dim3(4, 128, 1), 256, 0, stream>>>(
        o1b, f2wb, f2b, nullptr, nullptr, nullptr, (float*)d_out, 0, 0, 0);
}